// Round 7
// baseline (177.094 us; speedup 1.0000x reference)
//
#include <hip/hip_runtime.h>
#include <math.h>

#define PGT 10000
#define CNT0 0x7F7F7F7Fu

// ws layout (bytes):
//   0                  done counter (K2 only; memset 0x7F -> CNT0)
//   [256, 480256)      gpmin   u32[3*4*10000] float-bits  (memset 0x7F -> 3.39e38)
//   [480256, 506176)   pg0min  u64[3240]  ((distbits<<32)|idx), atomicMin merge (n==0)
//   [506176, 545056)   pgnmin  u32[3*3240] distbits, atomicMin merge (n=1..3)
//   [545280, +3984)    part    double[498], pre-scaled, plain stores
// part slots: lap/move [0,104) bce [104,168) edge [168,321) norm [321,474)
//             pgred [474,486) gpred [486,498)
#define NSLOT 498

static __device__ __forceinline__ float waveReduceSum(float v) {
#pragma unroll
    for (int o = 32; o; o >>= 1) v += __shfl_down(v, o);
    return v;
}
static __device__ __forceinline__ double waveReduceSumD(double v) {
#pragma unroll
    for (int o = 32; o; o >>= 1) v += __shfl_down(v, o);
    return v;
}
static __device__ __forceinline__ float blockReduceF(float v, float* red) {
    v = waveReduceSum(v);
    __syncthreads();
    if ((threadIdx.x & 63) == 0) red[threadIdx.x >> 6] = v;
    __syncthreads();
    return red[0] + red[1] + red[2] + red[3];
}
static __device__ __forceinline__ double blockReduceD(double v, double* red) {
    v = waveReduceSumD(v);
    __syncthreads();
    if ((threadIdx.x & 63) == 0) red[threadIdx.x >> 6] = v;
    __syncthreads();
    return red[0] + red[1] + red[2] + red[3];
}

// ---------------- K1 ----------------
//  [0,2592)     fused chamfer: block = (level, n, pred-chunk of 128, q-chunk of 417)
//               gt q-chunk staged in LDS as (x,y,z,|q|^2); each wave holds 16 preds
//               with -0.5*|p|^2 folded into the FMA seed. Row-min -> registers ->
//               global atomicMin; col-min -> LDS ds_min -> global atomicMin.
//               lvl0: 2 pchunks, lvl1: 5, lvl2: 20; x 24 qchunks x 4 batches.
//  [2592,2644)  laplace+move (52)
//  [2644,2708)  BCE (64)
__global__ __launch_bounds__(256) void k1_kernel(
    const float* __restrict__ pc0, const float* __restrict__ pc1, const float* __restrict__ pc2,
    const float* __restrict__ pb0, const float* __restrict__ pb1, const float* __restrict__ pb2,
    const int* __restrict__ lp0, const int* __restrict__ lp1, const int* __restrict__ lp2,
    const float* __restrict__ gtp, const float* __restrict__ gimg, const float* __restrict__ rec,
    unsigned* __restrict__ gpmin, unsigned long long* __restrict__ pg0min,
    unsigned* __restrict__ pgnmin, double* __restrict__ part)
{
    __shared__ float4 s_gt[448];     // 7 iters x 64 lanes
    __shared__ unsigned s_col[448];
    __shared__ float s_red[4];
    const int b = blockIdx.x;
    const int tid = threadIdx.x;

    if (b < 2592) {
        // ----- decode (level, n, pchunk, qchunk) -----
        int level, n, pchunk, qchunk, Pl, loff; const float* P;
        if (b < 192)      { level = 0; Pl = 156;  loff = 0;   P = pc0; int t = b;       n = t / 48;  int r = t % 48;  pchunk = r / 24; qchunk = r % 24; }
        else if (b < 672) { level = 1; Pl = 618;  loff = 156; P = pc1; int t = b - 192; n = t / 120; int r = t % 120; pchunk = r / 24; qchunk = r % 24; }
        else              { level = 2; Pl = 2466; loff = 774; P = pc2; int t = b - 672; n = t / 480; int r = t % 480; pchunk = r / 24; qchunk = r % 24; }
        const int wave = tid >> 6, lane = tid & 63;
        const int qbeg = qchunk * 417;
        const float* g3 = gtp + (size_t)n * PGT * 3;

        // ----- stage gt chunk into LDS (x,y,z,|q|^2); pad slots get huge |q|^2 -----
        for (int i = tid; i < 448; i += 256) {
            int q = qbeg + i;
            float x = 0.f, y = 0.f, z = 0.f, s = 1e30f;
            if (q < PGT) {
                const float* ga = g3 + (size_t)q * 3;
                x = ga[0]; y = ga[1]; z = ga[2];
                s = fmaf(x, x, fmaf(y, y, z * z));
            }
            s_gt[i] = make_float4(x, y, z, s);
            s_col[i] = CNT0;
        }
        __syncthreads();

        const float* pn = P + (size_t)n * Pl * 3;
        const int pcbase = pchunk * 128;
        const int ngroups = (Pl - pcbase > 64) ? 2 : 1;

        for (int g = 0; g < ngroups; g++) {
            const int pbase = pcbase + g * 64 + wave * 16;
            float px[16], py[16], pz[16], pm[16];
#pragma unroll
            for (int j = 0; j < 16; j++) {
                int pi = pbase + j; bool val = (pi < Pl); int ps = val ? pi : 0;
                px[j] = pn[ps * 3 + 0]; py[j] = pn[ps * 3 + 1]; pz[j] = pn[ps * 3 + 2];
                pm[j] = val ? -0.5f * fmaf(px[j], px[j], fmaf(py[j], py[j], pz[j] * pz[j]))
                            : -1e30f;   // invalid pred -> d ~ +2e30, never wins any min
            }
            float bd[16];
#pragma unroll
            for (int j = 0; j < 16; j++) bd[j] = 3e38f;

            if (n == 0) {
                int bi[16];
#pragma unroll
                for (int j = 0; j < 16; j++) bi[j] = 0;
                for (int it = 0; it < 7; it++) {
                    float4 gq = s_gt[it * 64 + lane];
                    int q = qbeg + it * 64 + lane;
                    float cm = 3e38f;
#pragma unroll
                    for (int j = 0; j < 16; j++) {
                        float t = fmaf(px[j], gq.x, fmaf(py[j], gq.y, fmaf(pz[j], gq.z, pm[j])));
                        float d = fmaf(-2.f, t, gq.w);   // |p|^2+|q|^2-2p.q
                        if (d < bd[j]) { bd[j] = d; bi[j] = q; }
                        cm = fminf(cm, d);
                    }
                    atomicMin(&s_col[it * 64 + lane], __float_as_uint(fmaxf(cm, 0.f)));
                }
#pragma unroll
                for (int j = 0; j < 16; j++) {
#pragma unroll
                    for (int o = 1; o < 64; o <<= 1) {
                        float od = __shfl_xor(bd[j], o);
                        int   oi = __shfl_xor(bi[j], o);
                        if (od < bd[j] || (od == bd[j] && oi < bi[j])) { bd[j] = od; bi[j] = oi; }
                    }
                }
                if (lane == 0) {
#pragma unroll
                    for (int j = 0; j < 16; j++) {
                        int pi = pbase + j;
                        if (pi < Pl) {
                            unsigned db = __float_as_uint(fmaxf(bd[j], 0.f));
                            atomicMin(&pg0min[loff + pi],
                                      ((unsigned long long)db << 32) | (unsigned)bi[j]);
                        }
                    }
                }
            } else {
                for (int it = 0; it < 7; it++) {
                    float4 gq = s_gt[it * 64 + lane];
                    float cm = 3e38f;
#pragma unroll
                    for (int j = 0; j < 16; j++) {
                        float t = fmaf(px[j], gq.x, fmaf(py[j], gq.y, fmaf(pz[j], gq.z, pm[j])));
                        float d = fmaf(-2.f, t, gq.w);
                        bd[j] = fminf(bd[j], d);
                        cm = fminf(cm, d);
                    }
                    atomicMin(&s_col[it * 64 + lane], __float_as_uint(fmaxf(cm, 0.f)));
                }
#pragma unroll
                for (int j = 0; j < 16; j++) {
#pragma unroll
                    for (int o = 1; o < 64; o <<= 1) bd[j] = fminf(bd[j], __shfl_xor(bd[j], o));
                }
                if (lane == 0) {
#pragma unroll
                    for (int j = 0; j < 16; j++) {
                        int pi = pbase + j;
                        if (pi < Pl)
                            atomicMin(&pgnmin[(n - 1) * 3240 + loff + pi],
                                      __float_as_uint(fmaxf(bd[j], 0.f)));
                    }
                }
            }
        }
        // ----- col-min writeback (one atomic per (q, pred-chunk)) -----
        __syncthreads();
        unsigned* gm = gpmin + (size_t)(level * 4 + n) * PGT;
        int Qlen = PGT - qbeg; if (Qlen > 417) Qlen = 417;
        for (int ql = tid; ql < Qlen; ql += 256)
            atomicMin(&gm[qbeg + ql], s_col[ql]);
    }
    else if (b < 2644) {
        // ================= laplace + move =================
        int t = b - 2592;
        int level, Pl, bstart; const float* P; const float* B; const int* L;
        if (t < 3)       { level = 0; Pl = 156;  P = pc0; B = pb0; L = lp0; bstart = 0; }
        else if (t < 13) { level = 1; Pl = 618;  P = pc1; B = pb1; L = lp1; bstart = 3; }
        else             { level = 2; Pl = 2466; P = pc2; B = pb2; L = lp2; bstart = 13; }
        int item = (t - bstart) * 256 + tid;
        float lap_s = 0.f, mov_s = 0.f;
        if (item < 4 * Pl) {
            int n = item / Pl, p = item % Pl;
            const int* lr = L + p * 10;
            float cntv = (float)lr[9];
            const float* Bn = B + (size_t)n * Pl * 3;
            const float* Pn = P + (size_t)n * Pl * 3;
            float sbx = 0, sby = 0, sbz = 0, spx = 0, spy = 0, spz = 0;
#pragma unroll
            for (int k = 0; k < 8; k++) {
                int id = lr[k];
                if (id >= 0) {
                    sbx += Bn[id * 3 + 0]; sby += Bn[id * 3 + 1]; sbz += Bn[id * 3 + 2];
                    spx += Pn[id * 3 + 0]; spy += Pn[id * 3 + 1]; spz += Pn[id * 3 + 2];
                }
            }
            float bx = Bn[p * 3], by = Bn[p * 3 + 1], bz = Bn[p * 3 + 2];
            float vx = Pn[p * 3], vy = Pn[p * 3 + 1], vz = Pn[p * 3 + 2];
            float dx = (bx - sbx / cntv) - (vx - spx / cntv);
            float dy = (by - sby / cntv) - (vy - spy / cntv);
            float dz = (bz - sbz / cntv) - (vz - spz / cntv);
            lap_s = dx * dx + dy * dy + dz * dz;
            float mx = bx - vx, my = by - vy, mz = bz - vz;
            mov_s = mx * mx + my * my + mz * mz;
        }
        float lsum = blockReduceF(lap_s, s_red);
        float msum = blockReduceF(mov_s, s_red);
        if (tid == 0) {
            const double lc[3] = {0.2, 1.0, 1.0};
            double inv = 1.0 / (4.0 * (double)Pl);
            part[2 * t]     = (double)lsum * (0.5 * lc[level] * inv);
            part[2 * t + 1] = (level > 0) ? (double)msum * (0.1 * lc[level] * inv) : 0.0;
        }
    }
    else {
        // ================= BCE =================
        int t = b - 2644;
        const float4* g4 = (const float4*)gimg;
        const float4* r4 = (const float4*)rec;
        const int N4 = 602112 / 4;
        float s = 0.f;
        for (int i = t * 256 + tid; i < N4; i += 64 * 256) {
            float4 gv = g4[i], rv = r4[i];
            s -= gv.x * __logf(rv.x) + (1.f - gv.x) * __logf(1.f - rv.x);
            s -= gv.y * __logf(rv.y) + (1.f - gv.y) * __logf(1.f - rv.y);
            s -= gv.z * __logf(rv.z) + (1.f - gv.z) * __logf(1.f - rv.z);
            s -= gv.w * __logf(rv.w) + (1.f - gv.w) * __logf(1.f - rv.w);
        }
        float sum = blockReduceF(s, s_red);
        if (tid == 0) part[104 + t] = (double)sum / 602112.0;
    }
}

// ---------------- K2: edge+normal, pg/gp reduce, finalize ----------------
__global__ __launch_bounds__(256) void k2_kernel(
    const float* __restrict__ pc0, const float* __restrict__ pc1, const float* __restrict__ pc2,
    const int* __restrict__ e0, const int* __restrict__ e1, const int* __restrict__ e2,
    const float* __restrict__ gtn,
    const unsigned long long* __restrict__ pg0min, const unsigned* __restrict__ pgnmin,
    const unsigned* __restrict__ gpmin,
    double* __restrict__ part, unsigned* __restrict__ done, float* __restrict__ out)
{
    __shared__ float s_red[4];
    __shared__ double s_redd[4];
    __shared__ int s_flag;
    const int b = blockIdx.x, tid = threadIdx.x;
    if (b < 153) {
        int level, El, Pl, loff, bstart; const float* P; const int* E;
        if (b < 8)       { level = 0; El = 462;  Pl = 156;  loff = 0;   bstart = 0;  P = pc0; E = e0; }
        else if (b < 37) { level = 1; El = 1848; Pl = 618;  loff = 156; bstart = 8;  P = pc1; E = e1; }
        else             { level = 2; El = 7392; Pl = 2466; loff = 774; bstart = 37; P = pc2; E = e2; }
        int item = (b - bstart) * 256 + tid;
        float es = 0.f, ns = 0.f;
        if (item < 4 * El) {
            int n = item / El, e = item % El;
            int a = E[e * 2 + 0], b2 = E[e * 2 + 1];
            const float* Pn = P + (size_t)n * Pl * 3;
            float ax = Pn[a * 3], ay = Pn[a * 3 + 1], az = Pn[a * 3 + 2];
            float bx = Pn[b2 * 3], by = Pn[b2 * 3 + 1], bz = Pn[b2 * 3 + 2];
            float ex = ax - bx, ey = ay - by, ez = az - bz;
            float el2 = ex * ex + ey * ey + ez * ez;
            es = el2;
            float einv = 1.f / fmaxf(sqrtf(el2), 1e-12f);
            unsigned long long k = pg0min[loff + a];
            int ig = (int)(k & 0xFFFFFFFFull);
            const float* Nv = gtn + ((size_t)n * PGT + ig) * 3;
            float nx = Nv[0], ny = Nv[1], nz = Nv[2];
            float ninv = 1.f / fmaxf(sqrtf(nx * nx + ny * ny + nz * nz), 1e-12f);
            ns = fabsf((ex * nx + ey * ny + ez * nz) * einv * ninv);
        }
        float esum = blockReduceF(es, s_red);
        float nsum = blockReduceF(ns, s_red);
        if (tid == 0) {
            double inv = 1.0 / (4.0 * (double)El);
            part[168 + b] = (double)esum * (0.1 * inv);
            part[321 + b] = (double)nsum * (0.00016 * inv);
        }
    } else if (b < 165) {
        int i = b - 153, level = i >> 2, n = i & 3;
        int Pl = (level == 0) ? 156 : (level == 1) ? 618 : 2466;
        int loff = (level == 0) ? 0 : (level == 1) ? 156 : 774;
        double s = 0.0;
        if (n == 0) {
            for (int p = tid; p < Pl; p += 256)
                s += (double)__uint_as_float((unsigned)(pg0min[loff + p] >> 32));
        } else {
            const unsigned* base = &pgnmin[(n - 1) * 3240 + loff];
            for (int p = tid; p < Pl; p += 256)
                s += (double)__uint_as_float(base[p]);
        }
        s = blockReduceD(s, s_redd);
        if (tid == 0) part[474 + i] = s / (4.0 * (double)Pl);
    } else {
        int i = b - 165, level = i >> 2, n = i & 3;
        const unsigned* gm = gpmin + (size_t)(level * 4 + n) * PGT;
        double s = 0.0;
        for (int q = tid; q < PGT; q += 256) s += (double)__uint_as_float(gm[q]);
        s = blockReduceD(s, s_redd);
        if (tid == 0) part[486 + i] = s * (0.55 / (4.0 * (double)PGT));
    }
    // ----- last-done finalize (177 atomics on one line: proven fine) -----
    __threadfence();
    if (tid == 0) {
        unsigned old = atomicAdd(done, 1u);
        s_flag = (old == CNT0 + 176u) ? 1 : 0;
        __threadfence();
    }
    __syncthreads();
    if (s_flag) {
        double s = 0.0;
        for (int i = tid; i < NSLOT; i += 256) s += part[i];
        s = blockReduceD(s, s_redd);
        if (tid == 0) out[0] = (float)s;
    }
}

extern "C" void kernel_launch(void* const* d_in, const int* in_sizes, int n_in,
                              void* d_out, int out_size, void* d_ws, size_t ws_size,
                              hipStream_t stream) {
    const float *pc[3], *pb[3]; const int *ed[3], *lp[3];
    bool dict = (n_in >= 2 && in_sizes[1] == in_sizes[0]);   // dict vs signature order
    if (dict) {
        for (int i = 0; i < 3; i++) {
            pc[i] = (const float*)d_in[4 * i + 0];
            pb[i] = (const float*)d_in[4 * i + 1];
            ed[i] = (const int*)  d_in[4 * i + 2];
            lp[i] = (const int*)  d_in[4 * i + 3];
        }
    } else {
        for (int i = 0; i < 3; i++) {
            pc[i] = (const float*)d_in[i];
            pb[i] = (const float*)d_in[3 + i];
            ed[i] = (const int*)  d_in[6 + i];
            lp[i] = (const int*)  d_in[9 + i];
        }
    }
    const float* gtp  = (const float*)d_in[12];
    const float* gtn  = (const float*)d_in[13];
    const float* gimg = (const float*)d_in[14];
    const float* rec  = (const float*)d_in[15];

    unsigned*           done   = (unsigned*)d_ws;
    unsigned*           gpmin  = (unsigned*)((char*)d_ws + 256);
    unsigned long long* pg0min = (unsigned long long*)((char*)d_ws + 480256);
    unsigned*           pgnmin = (unsigned*)((char*)d_ws + 506176);
    double*             part   = (double*)((char*)d_ws + 545280);

    // one memset: done -> CNT0, gpmin/pg0min/pgnmin -> +huge bits
    hipMemsetAsync(d_ws, 0x7F, 545056, stream);

    k1_kernel<<<2708, 256, 0, stream>>>(pc[0], pc[1], pc[2], pb[0], pb[1], pb[2],
                                        lp[0], lp[1], lp[2], gtp, gimg, rec,
                                        gpmin, pg0min, pgnmin, part);
    k2_kernel<<<177, 256, 0, stream>>>(pc[0], pc[1], pc[2], ed[0], ed[1], ed[2],
                                       gtn, pg0min, pgnmin, gpmin, part, done, (float*)d_out);
}

// Round 8
// 151.206 us; speedup vs baseline: 1.1712x; 1.1712x over previous
//
#include <hip/hip_runtime.h>
#include <math.h>

#define PGT 10000
#define CNT0 0x7F7F7F7Fu

// ws layout (bytes):
//   0                  done counter (K2 only; memset 0x7F -> CNT0)
//   [256, 480256)      gpmin   u32[3*4*10000] float-bits  (memset 0x7F -> 3.39e38)
//   [480256, 506176)   pg0min  u64[3240]  ((distbits<<32)|idx), atomicMin merge (n==0)
//   [506176, 545056)   pgnmin  u32[3*3240] distbits, atomicMin merge (n=1..3)
//   [545280, +3984)    part    double[498], pre-scaled, plain stores
// part slots: lap/move [0,104) bce [104,168) edge [168,321) norm [321,474)
//             pgred [474,486) gpred [486,498)
#define NSLOT 498

static __device__ __forceinline__ float waveReduceSum(float v) {
#pragma unroll
    for (int o = 32; o; o >>= 1) v += __shfl_down(v, o);
    return v;
}
static __device__ __forceinline__ double waveReduceSumD(double v) {
#pragma unroll
    for (int o = 32; o; o >>= 1) v += __shfl_down(v, o);
    return v;
}
static __device__ __forceinline__ float blockReduceF(float v, float* red) {
    v = waveReduceSum(v);
    __syncthreads();
    if ((threadIdx.x & 63) == 0) red[threadIdx.x >> 6] = v;
    __syncthreads();
    return red[0] + red[1] + red[2] + red[3];
}
static __device__ __forceinline__ double blockReduceD(double v, double* red) {
    v = waveReduceSumD(v);
    __syncthreads();
    if ((threadIdx.x & 63) == 0) red[threadIdx.x >> 6] = v;
    __syncthreads();
    return red[0] + red[1] + red[2] + red[3];
}

// ---------------- K1 ----------------
//  [0,1680)     fused chamfer (r6 geometry + LDS gt staging + folded -p^2/2):
//               block = (level, n, pred-chunk of 96, q-chunk of 834)
//               gt chunk in LDS as (x,y,z,|q|^2), padded to 896 w/ sentinel;
//               8 preds/wave x 3 groups; row-min in regs -> global atomicMin;
//               col-min via LDS ds_min -> global atomicMin.
//  [1680,1732)  laplace+move (52)
//  [1732,1796)  BCE (64)
__global__ __launch_bounds__(256) void k1_kernel(
    const float* __restrict__ pc0, const float* __restrict__ pc1, const float* __restrict__ pc2,
    const float* __restrict__ pb0, const float* __restrict__ pb1, const float* __restrict__ pb2,
    const int* __restrict__ lp0, const int* __restrict__ lp1, const int* __restrict__ lp2,
    const float* __restrict__ gtp, const float* __restrict__ gimg, const float* __restrict__ rec,
    unsigned* __restrict__ gpmin, unsigned long long* __restrict__ pg0min,
    unsigned* __restrict__ pgnmin, double* __restrict__ part)
{
    __shared__ float4 s_gt[896];     // 14 iters x 64 lanes
    __shared__ unsigned s_col[896];
    __shared__ float s_red[4];
    const int b = blockIdx.x;
    const int tid = threadIdx.x;

    if (b < 1680) {
        // ----- decode (level, n, pchunk, qchunk) -----
        int level, n, pchunk, qchunk, Pl, loff; const float* P;
        if (b < 96)       { level = 0; Pl = 156;  loff = 0;   P = pc0; int t = b;       n = t / 24;  int r = t % 24;  pchunk = r / 12; qchunk = r % 12; }
        else if (b < 432) { level = 1; Pl = 618;  loff = 156; P = pc1; int t = b - 96;  n = t / 84;  int r = t % 84;  pchunk = r / 12; qchunk = r % 12; }
        else              { level = 2; Pl = 2466; loff = 774; P = pc2; int t = b - 432; n = t / 312; int r = t % 312; pchunk = r / 12; qchunk = r % 12; }
        const int wave = tid >> 6, lane = tid & 63;
        const int qbeg = qchunk * 834;
        const float* g3 = gtp + (size_t)n * PGT * 3;

        // ----- stage gt chunk (x,y,z,|q|^2); pads get huge |q|^2 sentinel -----
        for (int i = tid; i < 896; i += 256) {
            int q = qbeg + i;
            float x = 0.f, y = 0.f, z = 0.f, s = 1e30f;
            if (q < PGT) {
                const float* ga = g3 + (size_t)q * 3;
                x = ga[0]; y = ga[1]; z = ga[2];
                s = fmaf(x, x, fmaf(y, y, z * z));
            }
            s_gt[i] = make_float4(x, y, z, s);
            s_col[i] = CNT0;
        }
        __syncthreads();

        const float* pn = P + (size_t)n * Pl * 3;
        const int pcbase = pchunk * 96;
        int rem = Pl - pcbase;
        const int ngroups = (rem >= 96) ? 3 : ((rem + 31) >> 5);

        for (int g = 0; g < ngroups; g++) {
            const int pbase = pcbase + g * 32 + wave * 8;
            float px[8], py[8], pz[8], pm[8];
#pragma unroll
            for (int j = 0; j < 8; j++) {
                int pi = pbase + j; bool val = (pi < Pl); int ps = val ? pi : 0;
                px[j] = pn[ps * 3 + 0]; py[j] = pn[ps * 3 + 1]; pz[j] = pn[ps * 3 + 2];
                pm[j] = val ? -0.5f * fmaf(px[j], px[j], fmaf(py[j], py[j], pz[j] * pz[j]))
                            : -1e30f;   // invalid pred -> d ~ +2e30, never wins any min
            }
            float bd[8];
#pragma unroll
            for (int j = 0; j < 8; j++) bd[j] = 3e38f;

            if (n == 0) {
                int bi[8];
#pragma unroll
                for (int j = 0; j < 8; j++) bi[j] = 0;
#pragma unroll
                for (int it = 0; it < 14; it++) {
                    float4 gq = s_gt[it * 64 + lane];
                    int q = qbeg + it * 64 + lane;
                    float cm = 3e38f;
#pragma unroll
                    for (int j = 0; j < 8; j++) {
                        float t = fmaf(px[j], gq.x, fmaf(py[j], gq.y, fmaf(pz[j], gq.z, pm[j])));
                        float d = fmaf(-2.f, t, gq.w);   // |p|^2+|q|^2-2p.q
                        if (d < bd[j]) { bd[j] = d; bi[j] = q; }
                        cm = fminf(cm, d);
                    }
                    atomicMin(&s_col[it * 64 + lane], __float_as_uint(fmaxf(cm, 0.f)));
                }
#pragma unroll
                for (int j = 0; j < 8; j++) {
#pragma unroll
                    for (int o = 1; o < 64; o <<= 1) {
                        float od = __shfl_xor(bd[j], o);
                        int   oi = __shfl_xor(bi[j], o);
                        if (od < bd[j] || (od == bd[j] && oi < bi[j])) { bd[j] = od; bi[j] = oi; }
                    }
                }
                if (lane == 0) {
#pragma unroll
                    for (int j = 0; j < 8; j++) {
                        int pi = pbase + j;
                        if (pi < Pl) {
                            unsigned db = __float_as_uint(fmaxf(bd[j], 0.f));
                            atomicMin(&pg0min[loff + pi],
                                      ((unsigned long long)db << 32) | (unsigned)bi[j]);
                        }
                    }
                }
            } else {
#pragma unroll
                for (int it = 0; it < 14; it++) {
                    float4 gq = s_gt[it * 64 + lane];
                    float cm = 3e38f;
#pragma unroll
                    for (int j = 0; j < 8; j++) {
                        float t = fmaf(px[j], gq.x, fmaf(py[j], gq.y, fmaf(pz[j], gq.z, pm[j])));
                        float d = fmaf(-2.f, t, gq.w);
                        bd[j] = fminf(bd[j], d);
                        cm = fminf(cm, d);
                    }
                    atomicMin(&s_col[it * 64 + lane], __float_as_uint(fmaxf(cm, 0.f)));
                }
#pragma unroll
                for (int j = 0; j < 8; j++) {
#pragma unroll
                    for (int o = 1; o < 64; o <<= 1) bd[j] = fminf(bd[j], __shfl_xor(bd[j], o));
                }
                if (lane == 0) {
#pragma unroll
                    for (int j = 0; j < 8; j++) {
                        int pi = pbase + j;
                        if (pi < Pl)
                            atomicMin(&pgnmin[(n - 1) * 3240 + loff + pi],
                                      __float_as_uint(fmaxf(bd[j], 0.f)));
                    }
                }
            }
        }
        // ----- col-min writeback (one atomic per (q, pred-chunk)) -----
        __syncthreads();
        unsigned* gm = gpmin + (size_t)(level * 4 + n) * PGT;
        int Qlen = PGT - qbeg; if (Qlen > 834) Qlen = 834;
        for (int ql = tid; ql < Qlen; ql += 256)
            atomicMin(&gm[qbeg + ql], s_col[ql]);
    }
    else if (b < 1732) {
        // ================= laplace + move =================
        int t = b - 1680;
        int level, Pl, bstart; const float* P; const float* B; const int* L;
        if (t < 3)       { level = 0; Pl = 156;  P = pc0; B = pb0; L = lp0; bstart = 0; }
        else if (t < 13) { level = 1; Pl = 618;  P = pc1; B = pb1; L = lp1; bstart = 3; }
        else             { level = 2; Pl = 2466; P = pc2; B = pb2; L = lp2; bstart = 13; }
        int item = (t - bstart) * 256 + tid;
        float lap_s = 0.f, mov_s = 0.f;
        if (item < 4 * Pl) {
            int n = item / Pl, p = item % Pl;
            const int* lr = L + p * 10;
            float cntv = (float)lr[9];
            const float* Bn = B + (size_t)n * Pl * 3;
            const float* Pn = P + (size_t)n * Pl * 3;
            float sbx = 0, sby = 0, sbz = 0, spx = 0, spy = 0, spz = 0;
#pragma unroll
            for (int k = 0; k < 8; k++) {
                int id = lr[k];
                if (id >= 0) {
                    sbx += Bn[id * 3 + 0]; sby += Bn[id * 3 + 1]; sbz += Bn[id * 3 + 2];
                    spx += Pn[id * 3 + 0]; spy += Pn[id * 3 + 1]; spz += Pn[id * 3 + 2];
                }
            }
            float bx = Bn[p * 3], by = Bn[p * 3 + 1], bz = Bn[p * 3 + 2];
            float vx = Pn[p * 3], vy = Pn[p * 3 + 1], vz = Pn[p * 3 + 2];
            float dx = (bx - sbx / cntv) - (vx - spx / cntv);
            float dy = (by - sby / cntv) - (vy - spy / cntv);
            float dz = (bz - sbz / cntv) - (vz - spz / cntv);
            lap_s = dx * dx + dy * dy + dz * dz;
            float mx = bx - vx, my = by - vy, mz = bz - vz;
            mov_s = mx * mx + my * my + mz * mz;
        }
        float lsum = blockReduceF(lap_s, s_red);
        float msum = blockReduceF(mov_s, s_red);
        if (tid == 0) {
            const double lc[3] = {0.2, 1.0, 1.0};
            double inv = 1.0 / (4.0 * (double)Pl);
            part[2 * t]     = (double)lsum * (0.5 * lc[level] * inv);
            part[2 * t + 1] = (level > 0) ? (double)msum * (0.1 * lc[level] * inv) : 0.0;
        }
    }
    else {
        // ================= BCE =================
        int t = b - 1732;
        const float4* g4 = (const float4*)gimg;
        const float4* r4 = (const float4*)rec;
        const int N4 = 602112 / 4;
        float s = 0.f;
        for (int i = t * 256 + tid; i < N4; i += 64 * 256) {
            float4 gv = g4[i], rv = r4[i];
            s -= gv.x * __logf(rv.x) + (1.f - gv.x) * __logf(1.f - rv.x);
            s -= gv.y * __logf(rv.y) + (1.f - gv.y) * __logf(1.f - rv.y);
            s -= gv.z * __logf(rv.z) + (1.f - gv.z) * __logf(1.f - rv.z);
            s -= gv.w * __logf(rv.w) + (1.f - gv.w) * __logf(1.f - rv.w);
        }
        float sum = blockReduceF(s, s_red);
        if (tid == 0) part[104 + t] = (double)sum / 602112.0;
    }
}

// ---------------- K2: edge+normal, pg/gp reduce, finalize ----------------
__global__ __launch_bounds__(256) void k2_kernel(
    const float* __restrict__ pc0, const float* __restrict__ pc1, const float* __restrict__ pc2,
    const int* __restrict__ e0, const int* __restrict__ e1, const int* __restrict__ e2,
    const float* __restrict__ gtn,
    const unsigned long long* __restrict__ pg0min, const unsigned* __restrict__ pgnmin,
    const unsigned* __restrict__ gpmin,
    double* __restrict__ part, unsigned* __restrict__ done, float* __restrict__ out)
{
    __shared__ float s_red[4];
    __shared__ double s_redd[4];
    __shared__ int s_flag;
    const int b = blockIdx.x, tid = threadIdx.x;
    if (b < 153) {
        int level, El, Pl, loff, bstart; const float* P; const int* E;
        if (b < 8)       { level = 0; El = 462;  Pl = 156;  loff = 0;   bstart = 0;  P = pc0; E = e0; }
        else if (b < 37) { level = 1; El = 1848; Pl = 618;  loff = 156; bstart = 8;  P = pc1; E = e1; }
        else             { level = 2; El = 7392; Pl = 2466; loff = 774; bstart = 37; P = pc2; E = e2; }
        int item = (b - bstart) * 256 + tid;
        float es = 0.f, ns = 0.f;
        if (item < 4 * El) {
            int n = item / El, e = item % El;
            int a = E[e * 2 + 0], b2 = E[e * 2 + 1];
            const float* Pn = P + (size_t)n * Pl * 3;
            float ax = Pn[a * 3], ay = Pn[a * 3 + 1], az = Pn[a * 3 + 2];
            float bx = Pn[b2 * 3], by = Pn[b2 * 3 + 1], bz = Pn[b2 * 3 + 2];
            float ex = ax - bx, ey = ay - by, ez = az - bz;
            float el2 = ex * ex + ey * ey + ez * ez;
            es = el2;
            float einv = 1.f / fmaxf(sqrtf(el2), 1e-12f);
            unsigned long long k = pg0min[loff + a];
            int ig = (int)(k & 0xFFFFFFFFull);
            const float* Nv = gtn + ((size_t)n * PGT + ig) * 3;
            float nx = Nv[0], ny = Nv[1], nz = Nv[2];
            float ninv = 1.f / fmaxf(sqrtf(nx * nx + ny * ny + nz * nz), 1e-12f);
            ns = fabsf((ex * nx + ey * ny + ez * nz) * einv * ninv);
        }
        float esum = blockReduceF(es, s_red);
        float nsum = blockReduceF(ns, s_red);
        if (tid == 0) {
            double inv = 1.0 / (4.0 * (double)El);
            part[168 + b] = (double)esum * (0.1 * inv);
            part[321 + b] = (double)nsum * (0.00016 * inv);
        }
    } else if (b < 165) {
        int i = b - 153, level = i >> 2, n = i & 3;
        int Pl = (level == 0) ? 156 : (level == 1) ? 618 : 2466;
        int loff = (level == 0) ? 0 : (level == 1) ? 156 : 774;
        double s = 0.0;
        if (n == 0) {
            for (int p = tid; p < Pl; p += 256)
                s += (double)__uint_as_float((unsigned)(pg0min[loff + p] >> 32));
        } else {
            const unsigned* base = &pgnmin[(n - 1) * 3240 + loff];
            for (int p = tid; p < Pl; p += 256)
                s += (double)__uint_as_float(base[p]);
        }
        s = blockReduceD(s, s_redd);
        if (tid == 0) part[474 + i] = s / (4.0 * (double)Pl);
    } else {
        int i = b - 165, level = i >> 2, n = i & 3;
        const unsigned* gm = gpmin + (size_t)(level * 4 + n) * PGT;
        double s = 0.0;
        for (int q = tid; q < PGT; q += 256) s += (double)__uint_as_float(gm[q]);
        s = blockReduceD(s, s_redd);
        if (tid == 0) part[486 + i] = s * (0.55 / (4.0 * (double)PGT));
    }
    // ----- last-done finalize (177 atomics on one line: proven fine) -----
    __threadfence();
    if (tid == 0) {
        unsigned old = atomicAdd(done, 1u);
        s_flag = (old == CNT0 + 176u) ? 1 : 0;
        __threadfence();
    }
    __syncthreads();
    if (s_flag) {
        double s = 0.0;
        for (int i = tid; i < NSLOT; i += 256) s += part[i];
        s = blockReduceD(s, s_redd);
        if (tid == 0) out[0] = (float)s;
    }
}

extern "C" void kernel_launch(void* const* d_in, const int* in_sizes, int n_in,
                              void* d_out, int out_size, void* d_ws, size_t ws_size,
                              hipStream_t stream) {
    const float *pc[3], *pb[3]; const int *ed[3], *lp[3];
    bool dict = (n_in >= 2 && in_sizes[1] == in_sizes[0]);   // dict vs signature order
    if (dict) {
        for (int i = 0; i < 3; i++) {
            pc[i] = (const float*)d_in[4 * i + 0];
            pb[i] = (const float*)d_in[4 * i + 1];
            ed[i] = (const int*)  d_in[4 * i + 2];
            lp[i] = (const int*)  d_in[4 * i + 3];
        }
    } else {
        for (int i = 0; i < 3; i++) {
            pc[i] = (const float*)d_in[i];
            pb[i] = (const float*)d_in[3 + i];
            ed[i] = (const int*)  d_in[6 + i];
            lp[i] = (const int*)  d_in[9 + i];
        }
    }
    const float* gtp  = (const float*)d_in[12];
    const float* gtn  = (const float*)d_in[13];
    const float* gimg = (const float*)d_in[14];
    const float* rec  = (const float*)d_in[15];

    unsigned*           done   = (unsigned*)d_ws;
    unsigned*           gpmin  = (unsigned*)((char*)d_ws + 256);
    unsigned long long* pg0min = (unsigned long long*)((char*)d_ws + 480256);
    unsigned*           pgnmin = (unsigned*)((char*)d_ws + 506176);
    double*             part   = (double*)((char*)d_ws + 545280);

    // one memset: done -> CNT0, gpmin/pg0min/pgnmin -> +huge bits
    hipMemsetAsync(d_ws, 0x7F, 545056, stream);

    k1_kernel<<<1796, 256, 0, stream>>>(pc[0], pc[1], pc[2], pb[0], pb[1], pb[2],
                                        lp[0], lp[1], lp[2], gtp, gimg, rec,
                                        gpmin, pg0min, pgnmin, part);
    k2_kernel<<<177, 256, 0, stream>>>(pc[0], pc[1], pc[2], ed[0], ed[1], ed[2],
                                       gtn, pg0min, pgnmin, gpmin, part, done, (float*)d_out);
}